// Round 1
// baseline (636.819 us; speedup 1.0000x reference)
//
#include <hip/hip_runtime.h>

// Problem constants (fixed by setup_inputs)
static constexpr int Bb = 2, Nn = 128, Ll = 128, Hh = 8, Ee = 64;
static constexpr float SCALE = 0.125f;  // 1/sqrt(E)

// One block computes one 128x128 attention group:
//   P[r][c] = exp(SCALE * (mask?[r][c]) * dot(Q[r], K[c]))
//   Out[r][d] = (sum_c P[r][c] * V[c][d]) / (sum_c P[r][c])
// Q/K/V/Out all addressed as base + row*row_stride + e, with
//   base = b*(N*L*H*E) + idx*idx_stride + h*E.
// Temporal: idx=n (stride L*H*E), rows=l (stride H*E), mask=null, Out=V_t(ws)
// Spatial : idx=l (stride H*E), rows=n (stride L*H*E), mask[b][r][c], V=V_t
__global__ __launch_bounds__(256) void st_attn(
    const float* __restrict__ Qp, const float* __restrict__ Kp,
    const float* __restrict__ Vp, const float* __restrict__ Mp,
    float* __restrict__ Op, int idx_stride, int row_stride) {
  // Pt[c][r ^ (c & 0x1C)] : exp'd scores, transposed; XOR swizzle breaks
  // phase-1 write bank conflicts. Exactly 64 KiB -> 2 blocks/CU.
  __shared__ __align__(16) float Pt[128 * 128];

  const int g = blockIdx.x;
  const int b = g >> 10;          // g / (128*8)
  const int idx = (g >> 3) & 127;
  const int h = g & 7;
  const int base = b * (Nn * Ll * Hh * Ee) + idx * idx_stride + h * Ee;

  const int tid = threadIdx.x;
  const int ty = tid >> 4;  // 0..15 : row group (8 contiguous rows)
  const int tx = tid & 15;  // 0..15 : col phase (cols c = 16*j + tx)

  // ---------------- Phase 1: scores (8x8 register tile) ----------------
  float acc[8][8];
#pragma unroll
  for (int i = 0; i < 8; ++i)
#pragma unroll
    for (int j = 0; j < 8; ++j) acc[i][j] = 0.f;

  const float* qb = Qp + base + (ty * 8) * row_stride;
  const float* kb = Kp + base + tx * row_stride;

#pragma unroll 2
  for (int e4 = 0; e4 < Ee; e4 += 4) {
    float4 qv[8], kv[8];
#pragma unroll
    for (int i = 0; i < 8; ++i)
      qv[i] = *(const float4*)(qb + i * row_stride + e4);
#pragma unroll
    for (int j = 0; j < 8; ++j)
      kv[j] = *(const float4*)(kb + (j * 16) * row_stride + e4);
#pragma unroll
    for (int i = 0; i < 8; ++i)
#pragma unroll
      for (int j = 0; j < 8; ++j)
        acc[i][j] += qv[i].x * kv[j].x + qv[i].y * kv[j].y +
                     qv[i].z * kv[j].z + qv[i].w * kv[j].w;
  }

  // exp (optionally * mask) and write Pt[c][r^sw]
  const bool has_mask = (Mp != nullptr);
#pragma unroll
  for (int j = 0; j < 8; ++j) {
    const int c = j * 16 + tx;
    float m[8];
    if (has_mask) {
      const float* mrow = Mp + b * (Nn * Nn) + c;
#pragma unroll
      for (int i = 0; i < 8; ++i) m[i] = mrow[(ty * 8 + i) * Nn];
    }
    float p[8];
#pragma unroll
    for (int i = 0; i < 8; ++i) {
      float v = acc[i][j] * SCALE;
      if (has_mask) v *= m[i];
      p[i] = __expf(v);
    }
    const int sw = c & 0x1C;
    *(float4*)&Pt[c * 128 + ((ty * 8) ^ sw)] =
        make_float4(p[0], p[1], p[2], p[3]);
    *(float4*)&Pt[c * 128 + ((ty * 8 + 4) ^ sw)] =
        make_float4(p[4], p[5], p[6], p[7]);
  }
  __syncthreads();

  // ---------------- Phase 2: row sums (wave w owns rows 32w..32w+31) ----
  const int lane = tid & 63;
  const int w = tid >> 6;
  const int r2 = w * 32 + (lane & 31);
  const int chalf = lane >> 5;  // each half-wave sums 64 cols
  float s = 0.f;
  for (int cc = 0; cc < 64; ++cc) {
    const int c = chalf * 64 + cc;
    s += Pt[c * 128 + (r2 ^ (c & 0x1C))];
  }
  s += __shfl_xor(s, 32);
  const float inv = 1.0f / s;  // lane L holds inv for row 32w + (L&31)

  // ---------------- Phase 3: Out = P*V (8 rows x 4 cols per thread) -----
  float vacc[8][4];
#pragma unroll
  for (int i = 0; i < 8; ++i)
#pragma unroll
    for (int d = 0; d < 4; ++d) vacc[i][d] = 0.f;

  const float* vb = Vp + base + tx * 4;
  const int r0 = ty * 8;
#pragma unroll 4
  for (int c = 0; c < 128; ++c) {
    const int sw = c & 0x1C;
    const float4 pa = *(const float4*)&Pt[c * 128 + (r0 ^ sw)];
    const float4 pb = *(const float4*)&Pt[c * 128 + ((r0 + 4) ^ sw)];
    const float4 vv = *(const float4*)(vb + c * row_stride);
    const float pr[8] = {pa.x, pa.y, pa.z, pa.w, pb.x, pb.y, pb.z, pb.w};
#pragma unroll
    for (int i = 0; i < 8; ++i) {
      vacc[i][0] += pr[i] * vv.x;
      vacc[i][1] += pr[i] * vv.y;
      vacc[i][2] += pr[i] * vv.z;
      vacc[i][3] += pr[i] * vv.w;
    }
  }

  // Epilogue: normalize (inv fetched cross-lane) and store.
  float* ob = Op + base + r0 * row_stride + tx * 4;
#pragma unroll
  for (int i = 0; i < 8; ++i) {
    const float invi = __shfl(inv, (lane >> 4) * 8 + i);
    const float4 o = make_float4(vacc[i][0] * invi, vacc[i][1] * invi,
                                 vacc[i][2] * invi, vacc[i][3] * invi);
    *(float4*)(ob + i * row_stride) = o;
  }
}

extern "C" void kernel_launch(void* const* d_in, const int* in_sizes, int n_in,
                              void* d_out, int out_size, void* d_ws,
                              size_t ws_size, hipStream_t stream) {
  const float* Q = (const float*)d_in[0];
  const float* K = (const float*)d_in[1];
  const float* V = (const float*)d_in[2];
  const float* M = (const float*)d_in[3];
  float* out = (float*)d_out;
  float* Vt = (float*)d_ws;  // 64 MiB intermediate V_t in workspace

  dim3 grid(Bb * Nn * Hh), blk(256);  // 2048 blocks
  // Temporal: per (b,n,h), rows = l
  st_attn<<<grid, blk, 0, stream>>>(Q, K, V, nullptr, Vt,
                                    Ll * Hh * Ee /*n stride*/,
                                    Hh * Ee /*l stride*/);
  // Spatial: per (b,l,h), rows = n, V operand = V_t
  st_attn<<<grid, blk, 0, stream>>>(Q, K, Vt, M, out, Hh * Ee /*l stride*/,
                                    Ll * Hh * Ee /*n stride*/);
}

// Round 2
// 454.606 us; speedup vs baseline: 1.4008x; 1.4008x over previous
//
#include <hip/hip_runtime.h>

// Problem constants (fixed by setup_inputs)
static constexpr int Bb = 2, Nn = 128, Ll = 128, Hh = 8, Ee = 64;
static constexpr float SCALE = 0.125f;  // 1/sqrt(E)
static constexpr int KLD = 68;          // K LDS row stride (64 + 4 pad, 16B-aligned)

// One block computes one 128x128 attention group:
//   P[r][c] = exp(SCALE * (mask?[r][c]) * dot(Q[r], K[c]))
//   Out[r][d] = (sum_c P[r][c] * V[c][d]) / (sum_c P[r][c])
// Temporal: idx=n, rows=l (stride H*E), mask=null, Out=V_t(ws)
// Spatial : idx=l, rows=n (stride L*H*E), mask[b][r][c], V=V_t
__global__ __launch_bounds__(256) void st_attn(
    const float* __restrict__ Qp, const float* __restrict__ Kp,
    const float* __restrict__ Vp, const float* __restrict__ Mp,
    float* __restrict__ Op, int idx_stride, int row_stride) {
  // 64 KiB LDS, aliased: phase 0/1 use the first 34.8 KiB as the K tile
  // (stride-68 rows -> 2-way-max bank aliasing = free); after a barrier the
  // whole buffer becomes Pt[c][r ^ (c & 0x1C)] (exp'd scores, transposed).
  __shared__ __align__(16) float smem[128 * 128];
  float* Ksh = smem;
  float* Pt = smem;

  const int g = blockIdx.x;
  const int b = g >> 10;
  const int idx = (g >> 3) & 127;
  const int h = g & 7;
  const int base = b * (Nn * Ll * Hh * Ee) + idx * idx_stride + h * Ee;

  const int tid = threadIdx.x;
  const int ty = tid >> 4;  // 0..15 : row group (8 contiguous rows)
  const int tx = tid & 15;  // 0..15 : col phase (cols c = 16*j + tx)

  // ---------------- Phase 0: stage K tile into LDS (coalesced) ----------
  // 128 rows x 64 floats; lane-consecutive float4s cover full 256B rows.
#pragma unroll
  for (int it = 0; it < 8; ++it) {
    const int i4 = tid + it * 256;       // float4 index 0..2047
    const int r = i4 >> 4;               // row 0..127
    const int c4 = (i4 & 15) << 2;       // float offset 0..60
    const float4 v = *(const float4*)(Kp + base + r * row_stride + c4);
    *(float4*)&Ksh[r * KLD + c4] = v;
  }
  __syncthreads();

  // ---------------- Phase 1: scores (8x8 register tile) ----------------
  float acc[8][8];
#pragma unroll
  for (int i = 0; i < 8; ++i)
#pragma unroll
    for (int j = 0; j < 8; ++j) acc[i][j] = 0.f;

  const float* qb = Qp + base + (ty * 8) * row_stride;

#pragma unroll 2
  for (int e4 = 0; e4 < Ee; e4 += 4) {
    float4 qv[8], kv[8];
#pragma unroll
    for (int i = 0; i < 8; ++i)
      qv[i] = *(const float4*)(qb + i * row_stride + e4);
#pragma unroll
    for (int j = 0; j < 8; ++j)
      kv[j] = *(const float4*)&Ksh[(j * 16 + tx) * KLD + e4];
#pragma unroll
    for (int i = 0; i < 8; ++i)
#pragma unroll
      for (int j = 0; j < 8; ++j)
        acc[i][j] += qv[i].x * kv[j].x + qv[i].y * kv[j].y +
                     qv[i].z * kv[j].z + qv[i].w * kv[j].w;
  }
  __syncthreads();  // all K reads done before Pt overwrites the K region

  // exp (optionally * mask), accumulate register row-sums, write Pt[c][r^sw]
  const bool has_mask = (Mp != nullptr);
  float rowsum[8];
#pragma unroll
  for (int i = 0; i < 8; ++i) rowsum[i] = 0.f;

#pragma unroll
  for (int j = 0; j < 8; ++j) {
    const int c = j * 16 + tx;
    float m[8];
    if (has_mask) {
      const float* mrow = Mp + b * (Nn * Nn) + c;
#pragma unroll
      for (int i = 0; i < 8; ++i) m[i] = mrow[(ty * 8 + i) * Nn];
    }
    float p[8];
#pragma unroll
    for (int i = 0; i < 8; ++i) {
      float v = acc[i][j] * SCALE;
      if (has_mask) v *= m[i];
      p[i] = __expf(v);
      rowsum[i] += p[i];
    }
    const int sw = c & 0x1C;
    *(float4*)&Pt[c * 128 + ((ty * 8) ^ sw)] =
        make_float4(p[0], p[1], p[2], p[3]);
    *(float4*)&Pt[c * 128 + ((ty * 8 + 4) ^ sw)] =
        make_float4(p[4], p[5], p[6], p[7]);
  }

  // ---------------- Phase 2 (in-register): full row sums via shfl -------
  // Threads sharing ty are 16 consecutive lanes; xor-shfl {1,2,4,8} sums
  // all 128 columns of this thread's 8 rows. Each thread then owns inv[]
  // for exactly the rows it normalizes in the epilogue.
  float inv[8];
#pragma unroll
  for (int i = 0; i < 8; ++i) {
#pragma unroll
    for (int s = 1; s < 16; s <<= 1) rowsum[i] += __shfl_xor(rowsum[i], s);
    inv[i] = 1.0f / rowsum[i];
  }
  __syncthreads();  // Pt fully written before phase 3 reads

  // ---------------- Phase 3: Out = P*V (8 rows x 4 cols per thread) -----
  float vacc[8][4];
#pragma unroll
  for (int i = 0; i < 8; ++i)
#pragma unroll
    for (int d = 0; d < 4; ++d) vacc[i][d] = 0.f;

  const float* vb = Vp + base + tx * 4;
  const int r0 = ty * 8;
#pragma unroll 4
  for (int c = 0; c < 128; ++c) {
    const int sw = c & 0x1C;
    const float4 pa = *(const float4*)&Pt[c * 128 + (r0 ^ sw)];
    const float4 pb = *(const float4*)&Pt[c * 128 + ((r0 + 4) ^ sw)];
    const float4 vv = *(const float4*)(vb + c * row_stride);
    const float pr[8] = {pa.x, pa.y, pa.z, pa.w, pb.x, pb.y, pb.z, pb.w};
#pragma unroll
    for (int i = 0; i < 8; ++i) {
      vacc[i][0] += pr[i] * vv.x;
      vacc[i][1] += pr[i] * vv.y;
      vacc[i][2] += pr[i] * vv.z;
      vacc[i][3] += pr[i] * vv.w;
    }
  }

  // Epilogue: normalize with this thread's own inv[] and store.
  float* ob = Op + base + r0 * row_stride + tx * 4;
#pragma unroll
  for (int i = 0; i < 8; ++i) {
    const float4 o = make_float4(vacc[i][0] * inv[i], vacc[i][1] * inv[i],
                                 vacc[i][2] * inv[i], vacc[i][3] * inv[i]);
    *(float4*)(ob + i * row_stride) = o;
  }
}

extern "C" void kernel_launch(void* const* d_in, const int* in_sizes, int n_in,
                              void* d_out, int out_size, void* d_ws,
                              size_t ws_size, hipStream_t stream) {
  const float* Q = (const float*)d_in[0];
  const float* K = (const float*)d_in[1];
  const float* V = (const float*)d_in[2];
  const float* M = (const float*)d_in[3];
  float* out = (float*)d_out;
  float* Vt = (float*)d_ws;  // 64 MiB intermediate V_t in workspace

  dim3 grid(Bb * Nn * Hh), blk(256);  // 2048 blocks
  // Temporal: per (b,n,h), rows = l
  st_attn<<<grid, blk, 0, stream>>>(Q, K, V, nullptr, Vt,
                                    Ll * Hh * Ee /*n stride*/,
                                    Hh * Ee /*l stride*/);
  // Spatial: per (b,l,h), rows = n, V operand = V_t
  st_attn<<<grid, blk, 0, stream>>>(Q, K, Vt, M, out, Hh * Ee /*l stride*/,
                                    Ll * Hh * Ee /*n stride*/);
}

// Round 3
// 301.947 us; speedup vs baseline: 2.1090x; 1.5056x over previous
//
#include <hip/hip_runtime.h>

// Problem constants (fixed by setup_inputs)
static constexpr int Bb = 2, Nn = 128, Ll = 128, Hh = 8, Ee = 64;
static constexpr float SCALE = 0.125f;  // 1/sqrt(E)

typedef short short8 __attribute__((ext_vector_type(8)));   // 8 bf16 in 4 VGPRs
typedef float float4v __attribute__((ext_vector_type(4)));  // MFMA C/D

#define MFMA16(a, b, c) __builtin_amdgcn_mfma_f32_16x16x32_bf16(a, b, c, 0, 0, 0)

__device__ inline unsigned short bf16_rne(float f) {
  unsigned u = __builtin_bit_cast(unsigned, f);
  u += 0x7FFFu + ((u >> 16) & 1u);
  return (unsigned short)(u >> 16);
}

// Split 8 fp32 into bf16 hi (truncated) + bf16 lo (RNE of residual).
// hi*hi + hi*lo + lo*hi reconstructs the product to ~2^-15.5 rel.
__device__ inline void split8(float4 a, float4 b, short8& hi, short8& lo) {
  float f[8] = {a.x, a.y, a.z, a.w, b.x, b.y, b.z, b.w};
#pragma unroll
  for (int j = 0; j < 8; ++j) {
    unsigned u = __builtin_bit_cast(unsigned, f[j]);
    unsigned short h = (unsigned short)(u >> 16);
    hi[j] = (short)h;
    float hf = __builtin_bit_cast(float, (unsigned)h << 16);
    lo[j] = (short)bf16_rne(f[j] - hf);
  }
}

__device__ inline short8 pack4(const unsigned* p) {
  union { unsigned u[4]; short8 s; } t;
  t.u[0] = p[0]; t.u[1] = p[1]; t.u[2] = p[2]; t.u[3] = p[3];
  return t.s;  // u32 = 2 consecutive bf16 (low halfword = even k) = frag pair
}

// One block = one 128x128 attention group (b, idx, h).
//   P[r][c] = exp(SCALE * (mask?) * dot(Q[r],K[c]));  Out = (P*V) / rowsum(P)
// Temporal: idx=n, rows=l (stride H*E), mask=null, Out=V_t(ws)
// Spatial : idx=l, rows=n (stride L*H*E), mask[b][r][c], V=V_t
__global__ __launch_bounds__(256, 3) void st_attn(
    const float* __restrict__ Qp, const float* __restrict__ Kp,
    const float* __restrict__ Vp, const float* __restrict__ Mp,
    float* __restrict__ Op, int idx_stride, int row_stride) {
  // P (exp'd scores) as bf16, row-major, stride 130 halfwords (65 words, odd
  // -> ~2-4-way max bank aliasing on all access patterns).  33,280 B.
  __shared__ __align__(16) unsigned short Pb[128 * 130];
  // V^T as bf16: Vb[d][c], stride 130 halfwords.  16,640 B.  Total 49,920 B
  // -> 3 blocks/CU by LDS.
  __shared__ __align__(16) unsigned short Vb[64 * 130];

  const int g = blockIdx.x;
  const int b = g >> 10;
  const int idx = (g >> 3) & 127;
  const int h = g & 7;
  const int base = b * (Nn * Ll * Hh * Ee) + idx * idx_stride + h * Ee;

  const int tid = threadIdx.x;
  const int wave = tid >> 6;
  const int lane = tid & 63;
  const int tx = lane & 15;    // MFMA m/n lane index
  const int quad = lane >> 4;  // MFMA k-chunk / row-quad

  // ---- Stage V -> LDS transposed bf16 (coalesced global reads) ----------
#pragma unroll
  for (int it = 0; it < 8; ++it) {
    const int i4 = tid + it * 256;     // 0..2047
    const int c = i4 >> 4;             // V row 0..127
    const int d0 = (i4 & 15) << 2;     // V col 0..60
    const float4 v = *(const float4*)(Vp + base + c * row_stride + d0);
    Vb[(d0 + 0) * 130 + c] = bf16_rne(v.x);
    Vb[(d0 + 1) * 130 + c] = bf16_rne(v.y);
    Vb[(d0 + 2) * 130 + c] = bf16_rne(v.z);
    Vb[(d0 + 3) * 130 + c] = bf16_rne(v.w);
  }

  // ---- Q fragments (direct global, hi/lo split), rows 32w..32w+31 -------
  short8 qhi[2][2], qlo[2][2];
#pragma unroll
  for (int rt = 0; rt < 2; ++rt) {
    const float* qr = Qp + base + (wave * 32 + rt * 16 + tx) * row_stride;
#pragma unroll
    for (int ks = 0; ks < 2; ++ks) {
      const float4 a = *(const float4*)(qr + ks * 32 + quad * 8);
      const float4 c = *(const float4*)(qr + ks * 32 + quad * 8 + 4);
      split8(a, c, qhi[rt][ks], qlo[rt][ks]);
    }
  }

  // ---- Score GEMM: S = Q*K^T (split bf16, 3 MFMAs per k-step) -----------
  float4v acc[2][8];
#pragma unroll
  for (int rt = 0; rt < 2; ++rt)
#pragma unroll
    for (int ct = 0; ct < 8; ++ct) acc[rt][ct] = (float4v)(0.0f);

#pragma unroll
  for (int ct = 0; ct < 8; ++ct) {
    const float* kr = Kp + base + (ct * 16 + tx) * row_stride;
#pragma unroll
    for (int ks = 0; ks < 2; ++ks) {
      const float4 a = *(const float4*)(kr + ks * 32 + quad * 8);
      const float4 c = *(const float4*)(kr + ks * 32 + quad * 8 + 4);
      short8 khi, klo;
      split8(a, c, khi, klo);
#pragma unroll
      for (int rt = 0; rt < 2; ++rt) {
        acc[rt][ct] = MFMA16(qhi[rt][ks], khi, acc[rt][ct]);
        acc[rt][ct] = MFMA16(qhi[rt][ks], klo, acc[rt][ct]);
        acc[rt][ct] = MFMA16(qlo[rt][ks], khi, acc[rt][ct]);
      }
    }
  }

  // ---- Softmax epilogue: scale/mask/exp, fp32 rowsums, P -> LDS bf16 ----
  const bool has_mask = (Mp != nullptr);
  const int mb = b * (Nn * Nn);
  float rowsum[2][4];
#pragma unroll
  for (int rt = 0; rt < 2; ++rt)
#pragma unroll
    for (int e = 0; e < 4; ++e) rowsum[rt][e] = 0.f;

#pragma unroll
  for (int rt = 0; rt < 2; ++rt) {
    const int rowb = wave * 32 + rt * 16 + quad * 4;  // C/D row = quad*4+reg
#pragma unroll
    for (int ct = 0; ct < 8; ++ct) {
      const int col = ct * 16 + tx;  // C/D col = lane&15
      float mv[4];
      if (has_mask) {
#pragma unroll
        for (int e = 0; e < 4; ++e) mv[e] = Mp[mb + (rowb + e) * 128 + col];
      }
#pragma unroll
      for (int e = 0; e < 4; ++e) {
        float p = acc[rt][ct][e] * SCALE;
        if (has_mask) p *= mv[e];
        p = __expf(p);
        rowsum[rt][e] += p;  // exact fp32 denominator (pre-rounding)
        Pb[(rowb + e) * 130 + col] = bf16_rne(p);
      }
    }
  }

  // Row sums complete across the 16 tx lanes of each quad group.
  float inv[2][4];
#pragma unroll
  for (int rt = 0; rt < 2; ++rt)
#pragma unroll
    for (int e = 0; e < 4; ++e) {
      float s = rowsum[rt][e];
#pragma unroll
      for (int d = 1; d < 16; d <<= 1) s += __shfl_xor(s, d);
      inv[rt][e] = 1.0f / s;
    }

  __syncthreads();  // Vb fully staged + Pb fully written

  // ---- PV GEMM: O = P*V, A = P rows (this wave's own), B = V^T rows -----
  float4v accO[2][4];
#pragma unroll
  for (int rt = 0; rt < 2; ++rt)
#pragma unroll
    for (int dt = 0; dt < 4; ++dt) accO[rt][dt] = (float4v)(0.0f);

#pragma unroll
  for (int ks = 0; ks < 4; ++ks) {
    short8 pA[2];
#pragma unroll
    for (int rt = 0; rt < 2; ++rt) {
      const unsigned* pw = (const unsigned*)Pb +
                           (wave * 32 + rt * 16 + tx) * 65 + ks * 16 + quad * 4;
      pA[rt] = pack4(pw);
    }
#pragma unroll
    for (int dt = 0; dt < 4; ++dt) {
      const unsigned* vw =
          (const unsigned*)Vb + (dt * 16 + tx) * 65 + ks * 16 + quad * 4;
      const short8 vB = pack4(vw);
      accO[0][dt] = MFMA16(pA[0], vB, accO[0][dt]);
      accO[1][dt] = MFMA16(pA[1], vB, accO[1][dt]);
    }
  }

  // ---- Normalize + store ------------------------------------------------
#pragma unroll
  for (int rt = 0; rt < 2; ++rt) {
    const int rowb = wave * 32 + rt * 16 + quad * 4;
#pragma unroll
    for (int dt = 0; dt < 4; ++dt) {
#pragma unroll
      for (int e = 0; e < 4; ++e) {
        Op[base + (rowb + e) * row_stride + dt * 16 + tx] =
            accO[rt][dt][e] * inv[rt][e];
      }
    }
  }
}

extern "C" void kernel_launch(void* const* d_in, const int* in_sizes, int n_in,
                              void* d_out, int out_size, void* d_ws,
                              size_t ws_size, hipStream_t stream) {
  const float* Q = (const float*)d_in[0];
  const float* K = (const float*)d_in[1];
  const float* V = (const float*)d_in[2];
  const float* M = (const float*)d_in[3];
  float* out = (float*)d_out;
  float* Vt = (float*)d_ws;  // 64 MiB intermediate V_t in workspace

  dim3 grid(Bb * Nn * Hh), blk(256);  // 2048 blocks
  // Temporal: per (b,n,h), rows = l
  st_attn<<<grid, blk, 0, stream>>>(Q, K, V, nullptr, Vt,
                                    Ll * Hh * Ee /*n stride*/,
                                    Hh * Ee /*l stride*/);
  // Spatial: per (b,l,h), rows = n, V operand = V_t
  st_attn<<<grid, blk, 0, stream>>>(Q, K, Vt, M, out, Hh * Ee /*l stride*/,
                                    Ll * Hh * Ee /*n stride*/);
}